// Round 1
// baseline (574.454 us; speedup 1.0000x reference)
//
#include <hip/hip_runtime.h>

#define B_ 1024
#define L_ 50
#define K_ 20
#define D_ 64
#define N_ITEMS 100000
#define N4 (N_ITEMS * D_ / 4)
#define CONV_BLOCKS 6250
#define ALPHA 0.2f

typedef __bf16 bf16x8 __attribute__((ext_vector_type(8)));
typedef float f32x4 __attribute__((ext_vector_type(4)));
typedef unsigned short u16x4 __attribute__((ext_vector_type(4)));

// round-to-nearest-even f32 -> bf16 bits
__device__ __forceinline__ unsigned short f2b(float f) {
    union { float f; unsigned int u; } x; x.f = f;
    unsigned int r = (x.u + 0x7FFFu + ((x.u >> 16) & 1u)) >> 16;
    return (unsigned short)r;
}

// Classic GCN 6-step DPP wave64 sum-reduce: result lands in lane 63,
// then readlane broadcasts it as a wave-uniform value. Pure VALU
// (per-SIMD pipe) instead of ds_bpermute (CU-shared LDS pipe) — at
// 1 wave/SIMD occupancy the LDS latency was fully exposed.
#define DPP_ADD(x, ctrl, rmask, bctrl)                                        \
    x += __int_as_float(__builtin_amdgcn_update_dpp(                          \
        0, __float_as_int(x), ctrl, rmask, 0xF, bctrl))

__device__ __forceinline__ float wave_sum_u(float x) {
    DPP_ADD(x, 0x111, 0xF, true);   // row_shr:1
    DPP_ADD(x, 0x112, 0xF, true);   // row_shr:2
    DPP_ADD(x, 0x114, 0xF, true);   // row_shr:4
    DPP_ADD(x, 0x118, 0xF, true);   // row_shr:8  -> lane15 of each row = row sum
    DPP_ADD(x, 0x142, 0xA, false);  // row_bcast:15 into rows 1,3
    DPP_ADD(x, 0x143, 0xC, false);  // row_bcast:31 into rows 2,3 -> lane63 total
    return __int_as_float(__builtin_amdgcn_readlane(__float_as_int(x), 63));
}

// ---------------- kernel 1: fused convert (fp32->bf16) + recurrence --------
// blockIdx < B_  : one wave per batch element; lane = d; mem[k] in registers.
// blockIdx >= B_ : fp32->bf16 conversion of item_table (independent work that
//                  backfills the SIMDs recur's lone waves leave idle).
__global__ __launch_bounds__(64) void fused_front_kernel(
    const float* __restrict__ item_table, const float* __restrict__ user_table,
    const float* __restrict__ memory_init, const int* __restrict__ user_id,
    const int* __restrict__ seq, const int* __restrict__ seq_len,
    unsigned short* __restrict__ item_bf16, unsigned short* __restrict__ pu_out) {

    if (blockIdx.x >= B_) {
        // ---- convert path: grid-stride over float4s, 4 iters/thread ----
        int i = (int)(blockIdx.x - B_) * 64 + (int)threadIdx.x;
        const int stride = CONV_BLOCKS * 64;
#pragma unroll 4
        for (; i < N4; i += stride) {
            f32x4 v = __builtin_nontemporal_load((const f32x4*)item_table + i);
            u16x4 o;
            o.x = f2b(v.x); o.y = f2b(v.y); o.z = f2b(v.z); o.w = f2b(v.w);
            ((u16x4*)item_bf16)[i] = o;  // cached store: gemm re-reads this
        }
        return;
    }

    // ---- recurrence path ----
    const int b = blockIdx.x;
    const int lane = threadIdx.x;
    const int T = seq_len[b];
    float mem[K_];
#pragma unroll
    for (int k = 0; k < K_; ++k)
        mem[k] = memory_init[(b * K_ + k) * D_ + lane];

    const int* sq = seq + b * L_;
    float e_next = item_table[(size_t)sq[0] * D_ + lane];  // prefetch t=0

    for (int t = 0; t < T; ++t) {
        float e = e_next;
        int tn = (t + 1 < L_) ? (t + 1) : t;               // always-safe prefetch
        e_next = item_table[(size_t)sq[tn] * D_ + lane];

        float w[K_];
#pragma unroll
        for (int k = 0; k < K_; ++k) w[k] = wave_sum_u(mem[k] * e);
        // softmax over k (wave-uniform values)
        float mx = w[0];
#pragma unroll
        for (int k = 1; k < K_; ++k) mx = fmaxf(mx, w[k]);
        float s = 0.0f;
#pragma unroll
        for (int k = 0; k < K_; ++k) { w[k] = __expf(w[k] - mx); s += w[k]; }
        float inv = 1.0f / s;
        float er = 1.0f / (1.0f + __expf(-e));     // sigmoid(e)
        float t2 = __expf(2.0f * e);
        float ad = (t2 - 1.0f) / (t2 + 1.0f);      // tanh(e)
#pragma unroll
        for (int k = 0; k < K_; ++k) {
            float z = w[k] * inv;
            mem[k] = mem[k] * (1.0f - z * er) + z * ad;
        }
    }

    // final attention with the LAST item in seq (always index L-1)
    float last = item_table[(size_t)sq[L_ - 1] * D_ + lane];
    float w[K_];
#pragma unroll
    for (int k = 0; k < K_; ++k) w[k] = wave_sum_u(mem[k] * last);
    float mx = w[0];
#pragma unroll
    for (int k = 1; k < K_; ++k) mx = fmaxf(mx, w[k]);
    float s = 0.0f;
#pragma unroll
    for (int k = 0; k < K_; ++k) { w[k] = __expf(w[k] - mx); s += w[k]; }
    float inv = 1.0f / s;
    float p = 0.0f;
#pragma unroll
    for (int k = 0; k < K_; ++k) p += (w[k] * inv) * mem[k];

    float pu = user_table[(size_t)user_id[b] * D_ + lane] + ALPHA * p;
    pu_out[b * D_ + lane] = f2b(pu);
}

// ---------------- kernel 2: scores = pu @ item_table^T (bf16 MFMA) ----------
// OPERAND SWAP vs previous version: A = item rows (MFMA M-dim = n),
// B = pu rows (MFMA N-dim = m). D layout (m89/m97): row = (lane>>4)*4+reg -> n
// (contiguous over reg!), col = lane&15 -> m. So each subtile stores ONE
// float4 per lane (16 dwordx4 stores/thread instead of 64 dword stores),
// nontemporal since the 409.6 MB output is never re-read.
__global__ __launch_bounds__(256) void gemm_kernel(
    const unsigned short* __restrict__ itemb,  // N_ITEMS x 64 bf16
    const unsigned short* __restrict__ pub,    // 1024 x 64 bf16
    float* __restrict__ out) {
    const int lane = threadIdx.x & 63;
    const int wv = threadIdx.x >> 6;
    const int r = lane & 15;
    const int q = lane >> 4;
    const int m0 = blockIdx.x * 256 + wv * 64;
    const int n0 = blockIdx.y * 64;

    bf16x8 zf;
#pragma unroll
    for (int i = 0; i < 8; ++i) zf[i] = (__bf16)0.0f;

    bf16x8 ai[4][2];  // A-frags: item rows n0+sn*16+r
#pragma unroll
    for (int sn = 0; sn < 4; ++sn) {
        int n = n0 + sn * 16 + r;
        if (n < N_ITEMS) {
            const unsigned short* p = itemb + (size_t)n * 64 + q * 8;
            ai[sn][0] = *(const bf16x8*)(p);
            ai[sn][1] = *(const bf16x8*)(p + 32);
        } else {
            ai[sn][0] = zf;
            ai[sn][1] = zf;
        }
    }
    bf16x8 bp[4][2];  // B-frags: pu rows m0+sm*16+r
#pragma unroll
    for (int sm = 0; sm < 4; ++sm) {
        const unsigned short* p = pub + (m0 + sm * 16 + r) * 64 + q * 8;
        bp[sm][0] = *(const bf16x8*)(p);
        bp[sm][1] = *(const bf16x8*)(p + 32);
    }

#pragma unroll
    for (int sn = 0; sn < 4; ++sn) {
        int nb = n0 + sn * 16 + q * 4;  // this lane's 4 consecutive n
        bool ok = (n0 + sn * 16) < N_ITEMS;  // N_ITEMS % 16 == 0: whole subtile
#pragma unroll
        for (int sm = 0; sm < 4; ++sm) {
            f32x4 c = {0.0f, 0.0f, 0.0f, 0.0f};
            c = __builtin_amdgcn_mfma_f32_16x16x32_bf16(ai[sn][0], bp[sm][0], c, 0, 0, 0);
            c = __builtin_amdgcn_mfma_f32_16x16x32_bf16(ai[sn][1], bp[sm][1], c, 0, 0, 0);
            if (ok) {
                int m = m0 + sm * 16 + r;
                __builtin_nontemporal_store(
                    c, (f32x4*)(out + (size_t)m * N_ITEMS + nb));
            }
        }
    }
}

extern "C" void kernel_launch(void* const* d_in, const int* in_sizes, int n_in,
                              void* d_out, int out_size, void* d_ws, size_t ws_size,
                              hipStream_t stream) {
    const float* item_table  = (const float*)d_in[0];
    const float* user_table  = (const float*)d_in[1];
    const float* memory_init = (const float*)d_in[2];
    const int*   user_id     = (const int*)d_in[3];
    const int*   seq         = (const int*)d_in[4];
    const int*   seq_len     = (const int*)d_in[5];
    float* out = (float*)d_out;

    unsigned short* item_bf16 = (unsigned short*)d_ws;            // 12.8 MB
    unsigned short* pu_bf16   = item_bf16 + (size_t)N_ITEMS * D_; // 128 KB

    fused_front_kernel<<<dim3(B_ + CONV_BLOCKS), dim3(64), 0, stream>>>(
        item_table, user_table, memory_init, user_id, seq, seq_len,
        item_bf16, pu_bf16);
    gemm_kernel<<<dim3(4, (N_ITEMS + 63) / 64), dim3(256), 0, stream>>>(
        item_bf16, pu_bf16, out);
}